// Round 3
// baseline (369.752 us; speedup 1.0000x reference)
//
#include <hip/hip_runtime.h>

#define D_MODEL   768
#define TWO_D     1536
#define SEQ       1024
#define N_LOOPS   4
#define RANK      8
#define D_STATE   16
#define EPS       1e-6f
#define BK        128
#define LDA       136   // u16 row stride: 272B = 68 words ≡ 4 mod 32 -> bank-balanced b128

typedef unsigned short u16;
typedef short s16x8 __attribute__((ext_vector_type(8)));
typedef unsigned short u16x4 __attribute__((ext_vector_type(4)));
typedef float f32x4 __attribute__((ext_vector_type(4)));

__device__ inline u16 f2bf(float f) {
    union { float f; unsigned u; } v; v.f = f;
    unsigned r = v.u + 0x7fffu + ((v.u >> 16) & 1u);   // RNE
    return (u16)(r >> 16);
}
__device__ inline float bf2f(u16 b) {
    union { unsigned u; float f; } v; v.u = ((unsigned)b) << 16;
    return v.f;
}

// ---------------- one-launch prep: W_in, Wout->bf16, h0, G ----------------
__global__ __launch_bounds__(256) void prep_all(
    const float* __restrict__ base, const float* __restrict__ lA,
    const float* __restrict__ lB,   const float* __restrict__ wout,
    const float* __restrict__ x,    const float* __restrict__ emb0,
    const float* __restrict__ th,   const float* __restrict__ Br,
    const float* __restrict__ Bi,   const float* __restrict__ Cr,
    const float* __restrict__ Ci,
    u16* __restrict__ Wbf, u16* __restrict__ Woutbf, float* __restrict__ G,
    float* __restrict__ hf, u16* __restrict__ hb)
{
    const int b = blockIdx.x, t = threadIdx.x;
    if (b < 1152) {                       // W_in = bf16(base + 2*(lB@lA))
        int i0 = (b * 256 + t) * 4;
        int r = i0 / D_MODEL, c = i0 % D_MODEL;
        float4 a = *reinterpret_cast<const float4*>(&base[i0]);
#pragma unroll
        for (int k = 0; k < RANK; ++k) {
            float bk = 2.0f * lB[r * RANK + k];
            const float4 av = *reinterpret_cast<const float4*>(&lA[k * D_MODEL + c]);
            a.x += bk * av.x; a.y += bk * av.y; a.z += bk * av.z; a.w += bk * av.w;
        }
        u16x4 o; o.x = f2bf(a.x); o.y = f2bf(a.y); o.z = f2bf(a.z); o.w = f2bf(a.w);
        *reinterpret_cast<u16x4*>(&Wbf[i0]) = o;
    } else if (b < 2304) {                // Wout bf16 copy
        int i0 = ((b - 1152) * 256 + t) * 4;
        const float4 v = *reinterpret_cast<const float4*>(&wout[i0]);
        u16x4 o; o.x = f2bf(v.x); o.y = f2bf(v.y); o.z = f2bf(v.z); o.w = f2bf(v.w);
        *reinterpret_cast<u16x4*>(&Woutbf[i0]) = o;
    } else if (b < 3072) {                // h0 = x + emb0 (f32 + bf16)
        int i0 = ((b - 2304) * 256 + t) * 4;
        int d = i0 % D_MODEL;
        const float4 v = *reinterpret_cast<const float4*>(&x[i0]);
        const float4 e = *reinterpret_cast<const float4*>(&emb0[d]);
        float4 h = make_float4(v.x + e.x, v.y + e.y, v.z + e.z, v.w + e.w);
        *reinterpret_cast<float4*>(&hf[i0]) = h;
        u16x4 o; o.x = f2bf(h.x); o.y = f2bf(h.y); o.z = f2bf(h.z); o.w = f2bf(h.w);
        *reinterpret_cast<u16x4*>(&hb[i0]) = o;
    } else {                              // G_k
        int cd = (b - 3072) * 256 + t;
        if (cd >= TWO_D) return;
        float g0 = 0.f, g1 = 0.f, g2 = 0.f, g3 = 0.f;
        for (int s = 0; s < D_STATE; ++s) {
            int idx = cd * D_STATE + s;
            float tt = th[idx];
            float br = Br[idx], bi = Bi[idx];
            float cr = Cr[idx], ci = Ci[idx];
#pragma unroll
            for (int k = 0; k < 4; ++k) {
                float ck = cosf(k * tt), sk = sinf(k * tt);
                float er = ck * br - sk * bi;
                float ei = sk * br + ck * bi;
                float g  = cr * er - ci * ei;
                if (k == 0) g0 += g; else if (k == 1) g1 += g;
                else if (k == 2) g2 += g; else g3 += g;
            }
        }
        G[0 * TWO_D + cd] = g0; G[1 * TWO_D + cd] = g1;
        G[2 * TWO_D + cd] = g2; G[3 * TWO_D + cd] = g3;
    }
}

// ------- GEMM1 + fused y:  xin_i = h @ W_in^T (bf16);  y = sum_{j<=i} G[i-j] ⊙ xin_j -------
// 64x64 tile, BK=128, 4 waves (each 32x32 = 2x2 16x16x32 frags)
__global__ __launch_bounds__(256) void gemm1y_kernel(
    const u16* __restrict__ A,     // hbf [SEQ][D_MODEL]
    const u16* __restrict__ B,     // Wbf [TWO_D][D_MODEL]
    u16* __restrict__ xin,         // [N_LOOPS][SEQ][TWO_D]
    u16* __restrict__ ybf,         // [SEQ][TWO_D]
    const float* __restrict__ G,   // [4][TWO_D]
    const int li)
{
    __shared__ __align__(16) u16 Al[64 * LDA];
    __shared__ __align__(16) u16 Bl[64 * LDA];
    const int K = D_MODEL;
    const int t = threadIdx.x, bm = blockIdx.y, bn = blockIdx.x;
    const int lane = t & 63, w = t >> 6;
    const int wr = w >> 1, wc = w & 1;
    const int lr = lane & 15, kg = lane >> 4;

    const u16* Ab = A + (size_t)bm * 64 * K;
    const u16* Bb = B + (size_t)bn * 64 * K;
    uint4 pa[4], pb[4];
#pragma unroll
    for (int q = 0; q < 4; ++q) {
        int gid = q * 256 + t, row = gid >> 4, g = gid & 15;
        pa[q] = *reinterpret_cast<const uint4*>(Ab + (size_t)row * K + g * 8);
        pb[q] = *reinterpret_cast<const uint4*>(Bb + (size_t)row * K + g * 8);
    }
    f32x4 acc[2][2] = {};
    const int NKT = K / BK;                 // 6
    for (int kt = 0; kt < NKT; ++kt) {
#pragma unroll
        for (int q = 0; q < 4; ++q) {
            int gid = q * 256 + t, row = gid >> 4, g = gid & 15;
            *reinterpret_cast<uint4*>(&Al[row * LDA + g * 8]) = pa[q];
            *reinterpret_cast<uint4*>(&Bl[row * LDA + g * 8]) = pb[q];
        }
        __syncthreads();
        if (kt + 1 < NKT) {
            const int ko = (kt + 1) * BK;
#pragma unroll
            for (int q = 0; q < 4; ++q) {
                int gid = q * 256 + t, row = gid >> 4, g = gid & 15;
                pa[q] = *reinterpret_cast<const uint4*>(Ab + (size_t)row * K + ko + g * 8);
                pb[q] = *reinterpret_cast<const uint4*>(Bb + (size_t)row * K + ko + g * 8);
            }
        }
#pragma unroll
        for (int ks = 0; ks < BK / 32; ++ks) {
            const int co = ks * 32 + kg * 8;
            s16x8 a0 = *reinterpret_cast<const s16x8*>(&Al[(wr * 32 +      lr) * LDA + co]);
            s16x8 a1 = *reinterpret_cast<const s16x8*>(&Al[(wr * 32 + 16 + lr) * LDA + co]);
            s16x8 b0 = *reinterpret_cast<const s16x8*>(&Bl[(wc * 32 +      lr) * LDA + co]);
            s16x8 b1 = *reinterpret_cast<const s16x8*>(&Bl[(wc * 32 + 16 + lr) * LDA + co]);
            acc[0][0] = __builtin_amdgcn_mfma_f32_16x16x32_bf16(a0, b0, acc[0][0], 0, 0, 0);
            acc[0][1] = __builtin_amdgcn_mfma_f32_16x16x32_bf16(a0, b1, acc[0][1], 0, 0, 0);
            acc[1][0] = __builtin_amdgcn_mfma_f32_16x16x32_bf16(a1, b0, acc[1][0], 0, 0, 0);
            acc[1][1] = __builtin_amdgcn_mfma_f32_16x16x32_bf16(a1, b1, acc[1][1], 0, 0, 0);
        }
        __syncthreads();
    }
    // epilogue: C col = lane&15, row = (lane>>4)*4 + reg  [m89-verified]
    const int crow0 = bm * 64 + wr * 32 + kg * 4;
    const int ccol0 = bn * 64 + wc * 32 + lr;
    u16* xslot = xin + (size_t)li * SEQ * TWO_D;
#pragma unroll
    for (int n = 0; n < 2; ++n) {
        const int col = ccol0 + n * 16;
        const float g0 = G[col];
#pragma unroll
        for (int m = 0; m < 2; ++m)
#pragma unroll
            for (int r = 0; r < 4; ++r) {
                const int row = crow0 + m * 16 + r;
                const size_t off = (size_t)row * TWO_D + col;
                const float v = acc[m][n][r];
                xslot[off] = f2bf(v);
                float y = g0 * v;
                for (int j = 0; j < li; ++j)
                    y += G[(size_t)(li - j) * TWO_D + col] *
                         bf2f(xin[(size_t)j * SEQ * TWO_D + off]);
                ybf[off] = f2bf(y);
            }
    }
}

// ------- GEMM2 split-K=2: outpre[z] = y[:, z*768:(z+1)*768] @ Wout[:, z*768:(z+1)*768]^T -------
__global__ __launch_bounds__(256) void gemm2_kernel(
    const u16* __restrict__ A,     // ybf [SEQ][TWO_D]
    const u16* __restrict__ B,     // Woutbf [D_MODEL][TWO_D]
    float* __restrict__ Cp)        // [2][SEQ][D_MODEL]
{
    __shared__ __align__(16) u16 Al[64 * LDA];
    __shared__ __align__(16) u16 Bl[64 * LDA];
    const int K = TWO_D;
    const int t = threadIdx.x, bm = blockIdx.y, bn = blockIdx.x, kz = blockIdx.z;
    const int lane = t & 63, w = t >> 6;
    const int wr = w >> 1, wc = w & 1;
    const int lr = lane & 15, kg = lane >> 4;

    const u16* Ab = A + (size_t)bm * 64 * K + kz * (K / 2);
    const u16* Bb = B + (size_t)bn * 64 * K + kz * (K / 2);
    uint4 pa[4], pb[4];
#pragma unroll
    for (int q = 0; q < 4; ++q) {
        int gid = q * 256 + t, row = gid >> 4, g = gid & 15;
        pa[q] = *reinterpret_cast<const uint4*>(Ab + (size_t)row * K + g * 8);
        pb[q] = *reinterpret_cast<const uint4*>(Bb + (size_t)row * K + g * 8);
    }
    f32x4 acc[2][2] = {};
    const int NKT = (K / 2) / BK;           // 6
    for (int kt = 0; kt < NKT; ++kt) {
#pragma unroll
        for (int q = 0; q < 4; ++q) {
            int gid = q * 256 + t, row = gid >> 4, g = gid & 15;
            *reinterpret_cast<uint4*>(&Al[row * LDA + g * 8]) = pa[q];
            *reinterpret_cast<uint4*>(&Bl[row * LDA + g * 8]) = pb[q];
        }
        __syncthreads();
        if (kt + 1 < NKT) {
            const int ko = (kt + 1) * BK;
#pragma unroll
            for (int q = 0; q < 4; ++q) {
                int gid = q * 256 + t, row = gid >> 4, g = gid & 15;
                pa[q] = *reinterpret_cast<const uint4*>(Ab + (size_t)row * K + ko + g * 8);
                pb[q] = *reinterpret_cast<const uint4*>(Bb + (size_t)row * K + ko + g * 8);
            }
        }
#pragma unroll
        for (int ks = 0; ks < BK / 32; ++ks) {
            const int co = ks * 32 + kg * 8;
            s16x8 a0 = *reinterpret_cast<const s16x8*>(&Al[(wr * 32 +      lr) * LDA + co]);
            s16x8 a1 = *reinterpret_cast<const s16x8*>(&Al[(wr * 32 + 16 + lr) * LDA + co]);
            s16x8 b0 = *reinterpret_cast<const s16x8*>(&Bl[(wc * 32 +      lr) * LDA + co]);
            s16x8 b1 = *reinterpret_cast<const s16x8*>(&Bl[(wc * 32 + 16 + lr) * LDA + co]);
            acc[0][0] = __builtin_amdgcn_mfma_f32_16x16x32_bf16(a0, b0, acc[0][0], 0, 0, 0);
            acc[0][1] = __builtin_amdgcn_mfma_f32_16x16x32_bf16(a0, b1, acc[0][1], 0, 0, 0);
            acc[1][0] = __builtin_amdgcn_mfma_f32_16x16x32_bf16(a1, b0, acc[1][0], 0, 0, 0);
            acc[1][1] = __builtin_amdgcn_mfma_f32_16x16x32_bf16(a1, b1, acc[1][1], 0, 0, 0);
        }
        __syncthreads();
    }
    const int crow0 = bm * 64 + wr * 32 + kg * 4;
    const int ccol0 = bn * 64 + wc * 32 + lr;
    float* Cz = Cp + (size_t)kz * SEQ * D_MODEL;
#pragma unroll
    for (int m = 0; m < 2; ++m)
#pragma unroll
        for (int n = 0; n < 2; ++n)
#pragma unroll
            for (int r = 0; r < 4; ++r)
                Cz[(size_t)(crow0 + m * 16 + r) * D_MODEL + ccol0 + n * 16] = acc[m][n][r];
}

// ---------- fused epilogue: out = rmsnorm(op0+op1)*mw ; x' = rmsnorm(h+out)*lw ----------
__device__ inline float block_sum256(float v) {
    __shared__ float sm[4];
#pragma unroll
    for (int off = 32; off > 0; off >>= 1) v += __shfl_down(v, off, 64);
    __syncthreads();
    if ((threadIdx.x & 63) == 0) sm[threadIdx.x >> 6] = v;
    __syncthreads();
    return sm[0] + sm[1] + sm[2] + sm[3];
}

__global__ __launch_bounds__(256) void norm_kernel(
    const float* __restrict__ op0, const float* __restrict__ op1,
    const float* __restrict__ hprev,
    const float* __restrict__ mw,  const float* __restrict__ lw,
    const float* __restrict__ embn,
    float* __restrict__ dstf, u16* __restrict__ dstb)
{
    const int r = blockIdx.x;
    const int t = threadIdx.x;
    const size_t ro = (size_t)r * D_MODEL;
    float op[3], h[3];
    float ss = 0.f;
#pragma unroll
    for (int j = 0; j < 3; ++j) {
        int d = t + j * 256;
        op[j] = op0[ro + d] + op1[ro + d];
        h[j]  = hprev[ro + d];
        ss += op[j] * op[j];
    }
    ss = block_sum256(ss);
    const float rs1 = rsqrtf(ss * (1.0f / D_MODEL) + EPS);
    float tt[3];
    float ss2 = 0.f;
#pragma unroll
    for (int j = 0; j < 3; ++j) {
        int d = t + j * 256;
        tt[j] = h[j] + op[j] * rs1 * mw[d];
        ss2 += tt[j] * tt[j];
    }
    ss2 = block_sum256(ss2);
    const float rs2 = rsqrtf(ss2 * (1.0f / D_MODEL) + EPS);
#pragma unroll
    for (int j = 0; j < 3; ++j) {
        int d = t + j * 256;
        float xo = tt[j] * rs2 * lw[d];
        if (embn != nullptr) {
            float hn = xo + embn[d];
            dstf[ro + d] = hn;
            dstb[ro + d] = f2bf(hn);
        } else {
            dstf[ro + d] = xo;
        }
    }
}

// ------------------------------------------------------------------
extern "C" void kernel_launch(void* const* d_in, const int* in_sizes, int n_in,
                              void* d_out, int out_size, void* d_ws, size_t ws_size,
                              hipStream_t stream) {
    const float* x            = (const float*)d_in[0];
    const float* in_proj_base = (const float*)d_in[1];
    const float* lora_A       = (const float*)d_in[2];
    const float* lora_B       = (const float*)d_in[3];
    const float* A_theta      = (const float*)d_in[4];
    const float* B_real       = (const float*)d_in[5];
    const float* B_imag       = (const float*)d_in[6];
    const float* C_real       = (const float*)d_in[7];
    const float* C_imag       = (const float*)d_in[8];
    const float* out_proj_w   = (const float*)d_in[9];
    const float* mixer_w      = (const float*)d_in[10];
    const float* loop_w       = (const float*)d_in[11];
    const float* step_emb     = (const float*)d_in[12];
    float* out = (float*)d_out;

    char* p = (char*)d_ws;
    u16*   Wbf    = (u16*)p;   p += (size_t)TWO_D * D_MODEL * 2;
    u16*   Woutbf = (u16*)p;   p += (size_t)D_MODEL * TWO_D * 2;
    float* G      = (float*)p; p += (size_t)4 * TWO_D * 4;
    u16*   xin    = (u16*)p;   p += (size_t)N_LOOPS * SEQ * TWO_D * 2;
    u16*   ybf    = (u16*)p;   p += (size_t)SEQ * TWO_D * 2;
    float* hAf    = (float*)p; p += (size_t)SEQ * D_MODEL * 4;
    float* hBf    = (float*)p; p += (size_t)SEQ * D_MODEL * 4;
    u16*   hbf    = (u16*)p;   p += (size_t)SEQ * D_MODEL * 2;
    float* outpre = (float*)p; p += (size_t)2 * SEQ * D_MODEL * 4;   // split-K halves

    prep_all<<<3078, 256, 0, stream>>>(
        in_proj_base, lora_A, lora_B, out_proj_w, x, step_emb,
        A_theta, B_real, B_imag, C_real, C_imag,
        Wbf, Woutbf, G, hAf, hbf);

    float* hcur = hAf;
    float* hnxt = hBf;
    for (int i = 0; i < N_LOOPS; ++i) {
        const bool last = (i == N_LOOPS - 1);
        gemm1y_kernel<<<dim3(TWO_D / 64, SEQ / 64), 256, 0, stream>>>(
            hbf, Wbf, xin, ybf, G, i);
        gemm2_kernel<<<dim3(D_MODEL / 64, SEQ / 64, 2), 256, 0, stream>>>(
            ybf, Woutbf, outpre);
        norm_kernel<<<SEQ, 256, 0, stream>>>(
            outpre, outpre + (size_t)SEQ * D_MODEL, hcur, mixer_w, loop_w,
            last ? nullptr : (step_emb + (size_t)(i + 1) * D_MODEL),
            last ? out : hnxt,
            last ? nullptr : hbf);
        float* tmp = hcur; hcur = hnxt; hnxt = tmp;
    }
}

// Round 4
// 228.656 us; speedup vs baseline: 1.6171x; 1.6171x over previous
//
#include <hip/hip_runtime.h>

#define D_MODEL   768
#define TWO_D     1536
#define SEQ       1024
#define N_LOOPS   4
#define RANK      8
#define D_STATE   16
#define EPS       1e-6f

typedef unsigned short u16;
typedef short s16x8 __attribute__((ext_vector_type(8)));
typedef unsigned short u16x4 __attribute__((ext_vector_type(4)));
typedef float f32x4 __attribute__((ext_vector_type(4)));

__device__ inline u16 f2bf(float f) {
    union { float f; unsigned u; } v; v.f = f;
    unsigned r = v.u + 0x7fffu + ((v.u >> 16) & 1u);   // RNE
    return (u16)(r >> 16);
}
__device__ inline float bf2f(u16 b) {
    union { unsigned u; float f; } v; v.u = ((unsigned)b) << 16;
    return v.f;
}

// ---------------- one-launch prep: W_in, Wout->bf16, h0, G ----------------
__global__ __launch_bounds__(256) void prep_all(
    const float* __restrict__ base, const float* __restrict__ lA,
    const float* __restrict__ lB,   const float* __restrict__ wout,
    const float* __restrict__ x,    const float* __restrict__ emb0,
    const float* __restrict__ th,   const float* __restrict__ Br,
    const float* __restrict__ Bi,   const float* __restrict__ Cr,
    const float* __restrict__ Ci,
    u16* __restrict__ Wbf, u16* __restrict__ Woutbf, float* __restrict__ G,
    float* __restrict__ hf, u16* __restrict__ hb)
{
    const int b = blockIdx.x, t = threadIdx.x;
    if (b < 1152) {                       // W_in = bf16(base + 2*(lB@lA))
        int i0 = (b * 256 + t) * 4;
        int r = i0 / D_MODEL, c = i0 % D_MODEL;
        float4 a = *reinterpret_cast<const float4*>(&base[i0]);
#pragma unroll
        for (int k = 0; k < RANK; ++k) {
            float bk = 2.0f * lB[r * RANK + k];
            const float4 av = *reinterpret_cast<const float4*>(&lA[k * D_MODEL + c]);
            a.x += bk * av.x; a.y += bk * av.y; a.z += bk * av.z; a.w += bk * av.w;
        }
        u16x4 o; o.x = f2bf(a.x); o.y = f2bf(a.y); o.z = f2bf(a.z); o.w = f2bf(a.w);
        *reinterpret_cast<u16x4*>(&Wbf[i0]) = o;
    } else if (b < 2304) {                // Wout bf16 copy
        int i0 = ((b - 1152) * 256 + t) * 4;
        const float4 v = *reinterpret_cast<const float4*>(&wout[i0]);
        u16x4 o; o.x = f2bf(v.x); o.y = f2bf(v.y); o.z = f2bf(v.z); o.w = f2bf(v.w);
        *reinterpret_cast<u16x4*>(&Woutbf[i0]) = o;
    } else if (b < 3072) {                // h0 = x + emb0 (f32 + bf16)
        int i0 = ((b - 2304) * 256 + t) * 4;
        int d = i0 % D_MODEL;
        const float4 v = *reinterpret_cast<const float4*>(&x[i0]);
        const float4 e = *reinterpret_cast<const float4*>(&emb0[d]);
        float4 h = make_float4(v.x + e.x, v.y + e.y, v.z + e.z, v.w + e.w);
        *reinterpret_cast<float4*>(&hf[i0]) = h;
        u16x4 o; o.x = f2bf(h.x); o.y = f2bf(h.y); o.z = f2bf(h.z); o.w = f2bf(h.w);
        *reinterpret_cast<u16x4*>(&hb[i0]) = o;
    } else {                              // G_k
        int cd = (b - 3072) * 256 + t;
        if (cd >= TWO_D) return;
        float g0 = 0.f, g1 = 0.f, g2 = 0.f, g3 = 0.f;
        for (int s = 0; s < D_STATE; ++s) {
            int idx = cd * D_STATE + s;
            float tt = th[idx];
            float br = Br[idx], bi = Bi[idx];
            float cr = Cr[idx], ci = Ci[idx];
#pragma unroll
            for (int k = 0; k < 4; ++k) {
                float ck = cosf(k * tt), sk = sinf(k * tt);
                float er = ck * br - sk * bi;
                float ei = sk * br + ck * bi;
                float g  = cr * er - ci * ei;
                if (k == 0) g0 += g; else if (k == 1) g1 += g;
                else if (k == 2) g2 += g; else g3 += g;
            }
        }
        G[0 * TWO_D + cd] = g0; G[1 * TWO_D + cd] = g1;
        G[2 * TWO_D + cd] = g2; G[3 * TWO_D + cd] = g3;
    }
}

// ---------------- bf16 NT MFMA GEMM: C[M,N] = A[M,K] * B[N,K]^T ----------------
// 64x64 tile, BK=64, 256 threads (4 waves, each a 32x32 quadrant of 2x2 16x16 frags)
// SPLITK: blockIdx.z selects k-half; f32 output goes to Cv + z*SEQ*N.
template<int K, int SPLITK, bool OUT_BF16>
__global__ __launch_bounds__(256) void gemm_nt(
    const u16* __restrict__ A, const u16* __restrict__ B,
    void* __restrict__ Cv, const int N)
{
    __shared__ u16 Al[64][72];   // +8 pad: row stride 144B = 36 banks -> 2-way max
    __shared__ u16 Bl[64][72];
    const int t  = threadIdx.x;
    const int bm = blockIdx.y, bn = blockIdx.x, kz = blockIdx.z;
    const int lane = t & 63, w = t >> 6;
    const int wr = w >> 1, wc = w & 1;
    const int lr = lane & 15, kg = lane >> 4;

    const int KS = K / SPLITK;
    const int kbase = kz * KS;

    const int r0 = t >> 3;              // 0..31
    const int q0 = t & 7;               // 16B column within row
    const u16* Ag0 = A + (size_t)(bm * 64 + r0)      * K + kbase + q0 * 8;
    const u16* Ag1 = A + (size_t)(bm * 64 + r0 + 32) * K + kbase + q0 * 8;
    const u16* Bg0 = B + (size_t)(bn * 64 + r0)      * K + kbase + q0 * 8;
    const u16* Bg1 = B + (size_t)(bn * 64 + r0 + 32) * K + kbase + q0 * 8;

    uint4 ra0 = *reinterpret_cast<const uint4*>(Ag0);
    uint4 ra1 = *reinterpret_cast<const uint4*>(Ag1);
    uint4 rb0 = *reinterpret_cast<const uint4*>(Bg0);
    uint4 rb1 = *reinterpret_cast<const uint4*>(Bg1);

    f32x4 acc[2][2] = {};
    const int NKT = KS / 64;
    for (int kt = 0; kt < NKT; ++kt) {
        *reinterpret_cast<uint4*>(&Al[r0][q0 * 8])      = ra0;
        *reinterpret_cast<uint4*>(&Al[r0 + 32][q0 * 8]) = ra1;
        *reinterpret_cast<uint4*>(&Bl[r0][q0 * 8])      = rb0;
        *reinterpret_cast<uint4*>(&Bl[r0 + 32][q0 * 8]) = rb1;
        __syncthreads();
        if (kt + 1 < NKT) {                  // next-tile loads fly during MFMA
            const int ko = (kt + 1) * 64;
            ra0 = *reinterpret_cast<const uint4*>(Ag0 + ko);
            ra1 = *reinterpret_cast<const uint4*>(Ag1 + ko);
            rb0 = *reinterpret_cast<const uint4*>(Bg0 + ko);
            rb1 = *reinterpret_cast<const uint4*>(Bg1 + ko);
        }
#pragma unroll
        for (int ks = 0; ks < 2; ++ks) {
            const int ko = ks * 32 + kg * 8;
            s16x8 a0 = *reinterpret_cast<const s16x8*>(&Al[wr * 32 + lr][ko]);
            s16x8 a1 = *reinterpret_cast<const s16x8*>(&Al[wr * 32 + 16 + lr][ko]);
            s16x8 b0 = *reinterpret_cast<const s16x8*>(&Bl[wc * 32 + lr][ko]);
            s16x8 b1 = *reinterpret_cast<const s16x8*>(&Bl[wc * 32 + 16 + lr][ko]);
            acc[0][0] = __builtin_amdgcn_mfma_f32_16x16x32_bf16(a0, b0, acc[0][0], 0, 0, 0);
            acc[0][1] = __builtin_amdgcn_mfma_f32_16x16x32_bf16(a0, b1, acc[0][1], 0, 0, 0);
            acc[1][0] = __builtin_amdgcn_mfma_f32_16x16x32_bf16(a1, b0, acc[1][0], 0, 0, 0);
            acc[1][1] = __builtin_amdgcn_mfma_f32_16x16x32_bf16(a1, b1, acc[1][1], 0, 0, 0);
        }
        __syncthreads();
    }
    // epilogue: C col = lane&15, row = (lane>>4)*4 + reg  [m89-verified]
    const int crow0 = bm * 64 + wr * 32 + kg * 4;
    const int ccol0 = bn * 64 + wc * 32 + lr;
#pragma unroll
    for (int m = 0; m < 2; ++m)
#pragma unroll
        for (int n = 0; n < 2; ++n)
#pragma unroll
            for (int r = 0; r < 4; ++r) {
                const int row = crow0 + m * 16 + r;
                const int col = ccol0 + n * 16;
                const float v = acc[m][n][r];
                if (OUT_BF16) ((u16*)Cv)[(size_t)row * N + col] = f2bf(v);
                else ((float*)Cv)[(size_t)kz * SEQ * N + (size_t)row * N + col] = v;
            }
}

// ---------------- y = sum_j G[i-j] ⊙ x_in_j  (bf16 in/out, f32 math) ----------------
__global__ __launch_bounds__(256) void y_kernel(
    const u16* __restrict__ xin,     // [N_LOOPS][SEQ][TWO_D]
    const float* __restrict__ G,     // [4][TWO_D]
    const int nacc, u16* __restrict__ y)
{
    int i4 = blockIdx.x * 256 + threadIdx.x;        // 0 .. 1024*1536/4-1
    int base = i4 * 4;
    int cd = base % TWO_D;
    float s0 = 0.f, s1 = 0.f, s2 = 0.f, s3 = 0.f;
    for (int j = 0; j < nacc; ++j) {
        u16x4 v = *reinterpret_cast<const u16x4*>(&xin[(size_t)j * SEQ * TWO_D + base]);
        const float4 g = *reinterpret_cast<const float4*>(&G[(size_t)(nacc - 1 - j) * TWO_D + cd]);
        s0 += bf2f(v.x) * g.x; s1 += bf2f(v.y) * g.y;
        s2 += bf2f(v.z) * g.z; s3 += bf2f(v.w) * g.w;
    }
    u16x4 o; o.x = f2bf(s0); o.y = f2bf(s1); o.z = f2bf(s2); o.w = f2bf(s3);
    *reinterpret_cast<u16x4*>(&y[base]) = o;
}

// ---------- fused epilogue, wave-per-row: out = rmsnorm(op0+op1)*mw ; x' = rmsnorm(h+out)*lw ----------
__global__ __launch_bounds__(256) void norm_kernel(
    const float* __restrict__ op0, const float* __restrict__ op1,
    const float* __restrict__ hprev,
    const float* __restrict__ mw,  const float* __restrict__ lw,
    const float* __restrict__ embn,
    float* __restrict__ dstf, u16* __restrict__ dstb)
{
    const int r = blockIdx.x * 4 + (threadIdx.x >> 6);   // wave-per-row
    const int lane = threadIdx.x & 63;
    const size_t ro = (size_t)r * D_MODEL;
    float op[12], h[12];
    float ss = 0.f;
#pragma unroll
    for (int e = 0; e < 12; ++e) {
        int d = lane + e * 64;
        op[e] = op0[ro + d] + op1[ro + d];
        h[e]  = hprev[ro + d];
        ss += op[e] * op[e];
    }
#pragma unroll
    for (int off = 32; off > 0; off >>= 1) ss += __shfl_xor(ss, off, 64);
    const float rs1 = rsqrtf(ss * (1.0f / D_MODEL) + EPS);
    float tt[12];
    float ss2 = 0.f;
#pragma unroll
    for (int e = 0; e < 12; ++e) {
        int d = lane + e * 64;
        tt[e] = h[e] + op[e] * rs1 * mw[d];
        ss2 += tt[e] * tt[e];
    }
#pragma unroll
    for (int off = 32; off > 0; off >>= 1) ss2 += __shfl_xor(ss2, off, 64);
    const float rs2 = rsqrtf(ss2 * (1.0f / D_MODEL) + EPS);
#pragma unroll
    for (int e = 0; e < 12; ++e) {
        int d = lane + e * 64;
        float xo = tt[e] * rs2 * lw[d];
        if (embn != nullptr) {
            float hn = xo + embn[d];
            dstf[ro + d] = hn;
            dstb[ro + d] = f2bf(hn);
        } else {
            dstf[ro + d] = xo;
        }
    }
}

// ------------------------------------------------------------------
extern "C" void kernel_launch(void* const* d_in, const int* in_sizes, int n_in,
                              void* d_out, int out_size, void* d_ws, size_t ws_size,
                              hipStream_t stream) {
    const float* x            = (const float*)d_in[0];
    const float* in_proj_base = (const float*)d_in[1];
    const float* lora_A       = (const float*)d_in[2];
    const float* lora_B       = (const float*)d_in[3];
    const float* A_theta      = (const float*)d_in[4];
    const float* B_real       = (const float*)d_in[5];
    const float* B_imag       = (const float*)d_in[6];
    const float* C_real       = (const float*)d_in[7];
    const float* C_imag       = (const float*)d_in[8];
    const float* out_proj_w   = (const float*)d_in[9];
    const float* mixer_w      = (const float*)d_in[10];
    const float* loop_w       = (const float*)d_in[11];
    const float* step_emb     = (const float*)d_in[12];
    float* out = (float*)d_out;

    char* p = (char*)d_ws;
    u16*   Wbf    = (u16*)p;   p += (size_t)TWO_D * D_MODEL * 2;
    u16*   Woutbf = (u16*)p;   p += (size_t)D_MODEL * TWO_D * 2;
    float* G      = (float*)p; p += (size_t)4 * TWO_D * 4;
    u16*   xin    = (u16*)p;   p += (size_t)N_LOOPS * SEQ * TWO_D * 2;
    u16*   ybf    = (u16*)p;   p += (size_t)SEQ * TWO_D * 2;
    float* hAf    = (float*)p; p += (size_t)SEQ * D_MODEL * 4;
    float* hBf    = (float*)p; p += (size_t)SEQ * D_MODEL * 4;
    u16*   hbf    = (u16*)p;   p += (size_t)SEQ * D_MODEL * 2;
    float* outpre = (float*)p; p += (size_t)2 * SEQ * D_MODEL * 4;   // split-K halves

    prep_all<<<3078, 256, 0, stream>>>(
        in_proj_base, lora_A, lora_B, out_proj_w, x, step_emb,
        A_theta, B_real, B_imag, C_real, C_imag,
        Wbf, Woutbf, G, hAf, hbf);

    float* hcur = hAf;
    float* hnxt = hBf;
    for (int i = 0; i < N_LOOPS; ++i) {
        const bool last = (i == N_LOOPS - 1);
        gemm_nt<D_MODEL, 1, true><<<dim3(TWO_D / 64, SEQ / 64), 256, 0, stream>>>(
            hbf, Wbf, (void*)(xin + (size_t)i * SEQ * TWO_D), TWO_D);
        y_kernel<<<(SEQ * TWO_D / 4) / 256, 256, 0, stream>>>(xin, G, i + 1, ybf);
        gemm_nt<TWO_D, 2, false><<<dim3(D_MODEL / 64, SEQ / 64, 2), 256, 0, stream>>>(
            ybf, Woutbf, (void*)outpre, D_MODEL);
        norm_kernel<<<SEQ / 4, 256, 0, stream>>>(
            outpre, outpre + (size_t)SEQ * D_MODEL, hcur, mixer_w, loop_w,
            last ? nullptr : (step_emb + (size_t)(i + 1) * D_MODEL),
            last ? out : hnxt,
            last ? nullptr : hbf);
        float* tmp = hcur; hcur = hnxt; hnxt = tmp;
    }
}